// Round 2
// baseline (25.395 us; speedup 1.0000x reference)
//
#include <hip/hip_runtime.h>

#define NPTS 2048
#define DIM  32
#define RPB  4            // rows per block
#define T1   256          // threads, kernel 1
#define T2   256          // threads, kernel 2
#define LOG_M 7.6246189861593985   // log(2048)

// Kernel 1: per-row stats of the implicit cost matrix, via
//   C_ij = |x_i|^2 + |y_j|^2 - 2 x_i.y_j
//   R[i]    = sum_j exp(-C_ij)
//   Crow[i] = sum_j C_ij
// x-rows are block-uniform with constant indices -> live in SGPR/uniform regs,
// no LDS on the hot path. 512 blocks = 2 blocks/CU = 2 waves/SIMD.
__global__ __launch_bounds__(T1)
void sink_rowstats(const float* __restrict__ x, const float* __restrict__ y,
                   float* __restrict__ R, float* __restrict__ Crow) {
    __shared__ float redE[RPB][T1 / 64];
    __shared__ float redC[RPB][T1 / 64];

    const int tid = threadIdx.x;
    const int rowBase = blockIdx.x * RPB;

    // Hoist this block's x-rows + norms into registers (uniform addresses).
    float xr[RPB][DIM];
    float xn[RPB];
#pragma unroll
    for (int r = 0; r < RPB; ++r) {
        const float4* xp = (const float4*)(x + (rowBase + r) * DIM);
        float s = 0.f;
#pragma unroll
        for (int q = 0; q < DIM / 4; ++q) {
            float4 v = xp[q];
            xr[r][4*q+0] = v.x; xr[r][4*q+1] = v.y;
            xr[r][4*q+2] = v.z; xr[r][4*q+3] = v.w;
            s = fmaf(v.x, v.x, fmaf(v.y, v.y, fmaf(v.z, v.z, fmaf(v.w, v.w, s))));
        }
        xn[r] = s;
    }

    float accE[RPB], accC[RPB];
#pragma unroll
    for (int r = 0; r < RPB; ++r) { accE[r] = 0.f; accC[r] = 0.f; }

    for (int j = tid; j < NPTS; j += T1) {
        const float4* yp = (const float4*)(y + j * DIM);
        float yv[DIM];
        float yn = 0.f;
#pragma unroll
        for (int q = 0; q < DIM / 4; ++q) {
            float4 v = yp[q];
            yv[4*q+0] = v.x; yv[4*q+1] = v.y;
            yv[4*q+2] = v.z; yv[4*q+3] = v.w;
            yn = fmaf(v.x, v.x, fmaf(v.y, v.y, fmaf(v.z, v.z, fmaf(v.w, v.w, yn))));
        }
#pragma unroll
        for (int r = 0; r < RPB; ++r) {
            float dot = 0.f;
#pragma unroll
            for (int k = 0; k < DIM; ++k)
                dot = fmaf(xr[r][k], yv[k], dot);
            float c = fmaf(-2.f, dot, xn[r] + yn);
            accE[r] += __expf(-c);
            accC[r] += c;
        }
    }

    // 64-lane butterfly, then cross-wave via LDS
#pragma unroll
    for (int r = 0; r < RPB; ++r) {
#pragma unroll
        for (int off = 32; off >= 1; off >>= 1) {
            accE[r] += __shfl_xor(accE[r], off, 64);
            accC[r] += __shfl_xor(accC[r], off, 64);
        }
    }
    const int wave = tid >> 6;
    if ((tid & 63) == 0) {
#pragma unroll
        for (int r = 0; r < RPB; ++r) {
            redE[r][wave] = accE[r];
            redC[r][wave] = accC[r];
        }
    }
    __syncthreads();
    if (tid < RPB) {
        float e = 0.f, c = 0.f;
#pragma unroll
        for (int wv = 0; wv < T1 / 64; ++wv) { e += redE[tid][wv]; c += redC[tid][wv]; }
        R[rowBase + tid]    = e;
        Crow[rowBase + tid] = c;
    }
}

// Kernel 2: closed-form epilogue.
//   w_i  = log M + log R_i
//   c50  = lse_j(-49 w_j)
//   loss = sum_i exp(-50 w_i - c50) * Crow_i
// f32 hardware transcendentals, f64 accumulation only.
__global__ __launch_bounds__(T2)
void sink_finish(const float* __restrict__ R, const float* __restrict__ Crow,
                 float* __restrict__ out) {
    __shared__ float  smf[T2 / 64];
    __shared__ double smd[T2 / 64];
    const int tid = threadIdx.x;
    const int lane = tid & 63, wave = tid >> 6;
    const int NW = T2 / 64;

    float w[NPTS / T2];
    float cr[NPTS / T2];
#pragma unroll
    for (int r = 0; r < NPTS / T2; ++r) {
        int i = tid + r * T2;
        w[r]  = (float)LOG_M + logf(R[i]);
        cr[r] = Crow[i];
    }

    // m = max(-49 w)
    float m = -49.f * w[0];
#pragma unroll
    for (int r = 1; r < NPTS / T2; ++r) m = fmaxf(m, -49.f * w[r]);
#pragma unroll
    for (int off = 32; off >= 1; off >>= 1) m = fmaxf(m, __shfl_xor(m, off, 64));
    if (lane == 0) smf[wave] = m;
    __syncthreads();
    m = smf[0];
#pragma unroll
    for (int wv = 1; wv < NW; ++wv) m = fmaxf(m, smf[wv]);
    __syncthreads();

    // s = sum exp(-49 w - m)   (f32 exp, f64 accumulate)
    double s = 0.0;
#pragma unroll
    for (int r = 0; r < NPTS / T2; ++r)
        s += (double)__expf(fmaf(-49.f, w[r], -m));
#pragma unroll
    for (int off = 32; off >= 1; off >>= 1) s += __shfl_xor(s, off, 64);
    if (lane == 0) smd[wave] = s;
    __syncthreads();
    s = 0.0;
#pragma unroll
    for (int wv = 0; wv < NW; ++wv) s += smd[wv];
    const float c50 = m + logf((float)s);
    __syncthreads();

    // loss = sum exp(-50 w - c50) * Crow
    double loss = 0.0;
#pragma unroll
    for (int r = 0; r < NPTS / T2; ++r)
        loss += (double)__expf(fmaf(-50.f, w[r], -c50)) * (double)cr[r];
#pragma unroll
    for (int off = 32; off >= 1; off >>= 1) loss += __shfl_xor(loss, off, 64);
    if (lane == 0) smd[wave] = loss;
    __syncthreads();
    if (tid == 0) {
        double t = 0.0;
#pragma unroll
        for (int wv = 0; wv < NW; ++wv) t += smd[wv];
        out[0] = (float)t;
    }
}

extern "C" void kernel_launch(void* const* d_in, const int* in_sizes, int n_in,
                              void* d_out, int out_size, void* d_ws, size_t ws_size,
                              hipStream_t stream) {
    const float* x = (const float*)d_in[0];
    const float* y = (const float*)d_in[1];
    float* out = (float*)d_out;
    float* ws  = (float*)d_ws;     // 2*2048 floats = 16 KB
    float* R    = ws;
    float* Crow = ws + NPTS;

    sink_rowstats<<<NPTS / RPB, T1, 0, stream>>>(x, y, R, Crow);
    sink_finish<<<1, T2, 0, stream>>>(R, Crow, out);
}